// Round 1
// baseline (354.824 us; speedup 1.0000x reference)
//
#include <hip/hip_runtime.h>

static constexpr int IN_C  = 128;
static constexpr int HID   = 96;
static constexpr int OUT_C = 48;

// ---------------- CSR build ----------------

__global__ void k_count(const int* __restrict__ dst, int* __restrict__ cnt, int E) {
  int e = blockIdx.x * blockDim.x + threadIdx.x;
  if (e < E) atomicAdd(&cnt[dst[e]], 1);
}

// exclusive block scan (256/block), emits per-block total
__global__ void k_scan_block(const int* __restrict__ in, int* __restrict__ out_excl,
                             int* __restrict__ bsum, int n) {
  __shared__ int sm[256];
  int i = blockIdx.x * 256 + threadIdx.x;
  int v = (i < n) ? in[i] : 0;
  int val = v;
  sm[threadIdx.x] = val;
  __syncthreads();
  for (int off = 1; off < 256; off <<= 1) {
    int t = (threadIdx.x >= (unsigned)off) ? sm[threadIdx.x - off] : 0;
    __syncthreads();
    val += t;
    sm[threadIdx.x] = val;
    __syncthreads();
  }
  if (i < n) out_excl[i] = val - v;
  if (threadIdx.x == 255) bsum[blockIdx.x] = val;
}

__global__ void k_finish(int* __restrict__ rs, const int* __restrict__ boff,
                         int* __restrict__ cursor, const int* __restrict__ cnt,
                         float* __restrict__ dinv, int n) {
  int i = blockIdx.x * 256 + threadIdx.x;
  if (i >= n) return;
  int r = rs[i] + boff[blockIdx.x];
  rs[i] = r;
  cursor[i] = r;
  dinv[i] = rsqrtf((float)cnt[i] + 1.0f);   // deg includes self-loop, always >= 1
}

__global__ void k_fill(const int* __restrict__ src, const int* __restrict__ dst,
                       int* __restrict__ cursor, int* __restrict__ csr, int E) {
  int e = blockIdx.x * blockDim.x + threadIdx.x;
  if (e >= E) return;
  int p = atomicAdd(&cursor[dst[e]], 1);
  csr[p] = src[e];
}

// ---------------- GEMM: Y[N x M] = X[N x K] @ W[K x M] ----------------
// 4 rows x 4 cols per thread; W row chunks as float4 (wave-broadcast, cache-hot)

template <int K, int M>
__global__ __launch_bounds__(256) void k_gemm(const float* __restrict__ X,
                                              const float* __restrict__ W,
                                              float* __restrict__ Y, int N) {
  constexpr int JC = M / 4;
  int gid = blockIdx.x * blockDim.x + threadIdx.x;
  int rg = gid / JC;
  int jc = (gid - rg * JC) * 4;
  int r0 = rg * 4;
  if (r0 >= N) return;
  int r1 = min(r0 + 1, N - 1), r2 = min(r0 + 2, N - 1), r3 = min(r0 + 3, N - 1);
  const float* x0 = X + (size_t)r0 * K;
  const float* x1 = X + (size_t)r1 * K;
  const float* x2 = X + (size_t)r2 * K;
  const float* x3 = X + (size_t)r3 * K;
  float4 a0 = {0,0,0,0}, a1 = {0,0,0,0}, a2 = {0,0,0,0}, a3 = {0,0,0,0};
#pragma unroll 4
  for (int k = 0; k < K; ++k) {
    float4 w = *(const float4*)(W + k * M + jc);
    float v0 = x0[k], v1 = x1[k], v2 = x2[k], v3 = x3[k];
    a0.x = fmaf(v0, w.x, a0.x); a0.y = fmaf(v0, w.y, a0.y);
    a0.z = fmaf(v0, w.z, a0.z); a0.w = fmaf(v0, w.w, a0.w);
    a1.x = fmaf(v1, w.x, a1.x); a1.y = fmaf(v1, w.y, a1.y);
    a1.z = fmaf(v1, w.z, a1.z); a1.w = fmaf(v1, w.w, a1.w);
    a2.x = fmaf(v2, w.x, a2.x); a2.y = fmaf(v2, w.y, a2.y);
    a2.z = fmaf(v2, w.z, a2.z); a2.w = fmaf(v2, w.w, a2.w);
    a3.x = fmaf(v3, w.x, a3.x); a3.y = fmaf(v3, w.y, a3.y);
    a3.z = fmaf(v3, w.z, a3.z); a3.w = fmaf(v3, w.w, a3.w);
  }
  *(float4*)(Y + (size_t)r0 * M + jc) = a0;
  if (r0 + 1 < N) *(float4*)(Y + (size_t)(r0 + 1) * M + jc) = a1;
  if (r0 + 2 < N) *(float4*)(Y + (size_t)(r0 + 2) * M + jc) = a2;
  if (r0 + 3 < N) *(float4*)(Y + (size_t)(r0 + 3) * M + jc) = a3;
}

// ---------------- Aggregation: out[n,f] = dinv[n]*(dinv[n]*H[n,f] + sum_s dinv[s]*H[s,f]) + b[f]

template <int M, bool RELU>
__global__ __launch_bounds__(256) void k_agg(const float* __restrict__ H,
                                             const int* __restrict__ csr,
                                             const int* __restrict__ rs,
                                             const int* __restrict__ cnt,
                                             const float* __restrict__ dinv,
                                             const float* __restrict__ bias,
                                             float* __restrict__ out, int N) {
  int gid = blockIdx.x * blockDim.x + threadIdx.x;
  int n = gid / M;
  if (n >= N) return;
  int f = gid - n * M;
  float dn = dinv[n];
  float acc = dn * H[(size_t)n * M + f];      // self-loop term (pre-scaled once)
  int s0 = rs[n];
  int e = cnt[n];
  for (int i = 0; i < e; ++i) {
    int s = csr[s0 + i];
    acc = fmaf(dinv[s], H[(size_t)s * M + f], acc);
  }
  float r = fmaf(dn, acc, bias[f]);
  if (RELU) r = fmaxf(r, 0.0f);
  out[gid] = r;
}

// ---------------- launch ----------------

extern "C" void kernel_launch(void* const* d_in, const int* in_sizes, int n_in,
                              void* d_out, int out_size, void* d_ws, size_t ws_size,
                              hipStream_t stream) {
  const float* x  = (const float*)d_in[0];
  const int*   ei = (const int*)d_in[1];
  const float* W1 = (const float*)d_in[2];
  const float* b1 = (const float*)d_in[3];
  const float* W2 = (const float*)d_in[4];
  const float* b2 = (const float*)d_in[5];
  float* out = (float*)d_out;

  const int N = in_sizes[0] / IN_C;     // 50000
  const int E = in_sizes[1] / 2;        // 800000
  const int* src = ei;
  const int* dst = ei + E;

  char* ws = (char*)d_ws;
  size_t off = 0;
  auto alloc = [&](size_t bytes) -> void* {
    void* p = ws + off;
    off = (off + bytes + 255) & ~(size_t)255;
    return p;
  };
  int*   cnt    = (int*)alloc((size_t)N * 4);
  int*   rs     = (int*)alloc((size_t)N * 4);
  int*   cursor = (int*)alloc((size_t)N * 4);
  float* dinv   = (float*)alloc((size_t)N * 4);
  int*   bsum   = (int*)alloc(256 * 4);
  int*   boff   = (int*)alloc(256 * 4);
  int*   junk   = (int*)alloc(256 * 4);
  int*   csr    = (int*)alloc((size_t)E * 4);
  float* h1     = (float*)alloc((size_t)N * HID * 4);   // reused as h2 later
  float* h      = (float*)alloc((size_t)N * HID * 4);

  const int nbN = (N + 255) / 256;
  const int nbE = (E + 255) / 256;

  hipMemsetAsync(cnt, 0, (size_t)N * 4, stream);
  k_count<<<nbE, 256, 0, stream>>>(dst, cnt, E);
  k_scan_block<<<nbN, 256, 0, stream>>>(cnt, rs, bsum, N);
  k_scan_block<<<1, 256, 0, stream>>>(bsum, boff, junk, nbN);
  k_finish<<<nbN, 256, 0, stream>>>(rs, boff, cursor, cnt, dinv, N);
  k_fill<<<nbE, 256, 0, stream>>>(src, dst, cursor, csr, E);

  // layer 1: h1 = x @ W1 ; h = relu(agg(h1) + b1)
  {
    int threads = (N / 4 + (N % 4 ? 1 : 0)) * (HID / 4);
    k_gemm<IN_C, HID><<<(threads + 255) / 256, 256, 0, stream>>>(x, W1, h1, N);
    int t2 = N * HID;
    k_agg<HID, true><<<(t2 + 255) / 256, 256, 0, stream>>>(h1, csr, rs, cnt, dinv, b1, h, N);
  }
  // layer 2: h2 = h @ W2 (into h1 buffer) ; out = agg(h2) + b2
  {
    int threads = (N / 4 + (N % 4 ? 1 : 0)) * (OUT_C / 4);
    k_gemm<HID, OUT_C><<<(threads + 255) / 256, 256, 0, stream>>>(h, W2, h1, N);
    int t2 = N * OUT_C;
    k_agg<OUT_C, false><<<(t2 + 255) / 256, 256, 0, stream>>>(h1, csr, rs, cnt, dinv, b2, out, N);
  }
}

// Round 2
// 236.115 us; speedup vs baseline: 1.5028x; 1.5028x over previous
//
#include <hip/hip_runtime.h>

static constexpr int IN_C  = 128;
static constexpr int HID   = 96;
static constexpr int OUT_C = 48;

// ---------------- CSR build ----------------

__global__ void k_count(const int* __restrict__ dst, int* __restrict__ cnt, int E) {
  int e = blockIdx.x * blockDim.x + threadIdx.x;
  if (e < E) atomicAdd(&cnt[dst[e]], 1);
}

// exclusive block scan (256/block), emits per-block total
__global__ void k_scan_block(const int* __restrict__ in, int* __restrict__ out_excl,
                             int* __restrict__ bsum, int n) {
  __shared__ int sm[256];
  int i = blockIdx.x * 256 + threadIdx.x;
  int v = (i < n) ? in[i] : 0;
  int val = v;
  sm[threadIdx.x] = val;
  __syncthreads();
  for (int off = 1; off < 256; off <<= 1) {
    int t = (threadIdx.x >= (unsigned)off) ? sm[threadIdx.x - off] : 0;
    __syncthreads();
    val += t;
    sm[threadIdx.x] = val;
    __syncthreads();
  }
  if (i < n) out_excl[i] = val - v;
  if (threadIdx.x == 255) bsum[blockIdx.x] = val;
}

__global__ void k_finish(int* __restrict__ rs, const int* __restrict__ boff,
                         int* __restrict__ cursor, const int* __restrict__ cnt,
                         float* __restrict__ dinv, int n) {
  int i = blockIdx.x * 256 + threadIdx.x;
  if (i >= n) return;
  int r = rs[i] + boff[blockIdx.x];
  rs[i] = r;
  cursor[i] = r;
  dinv[i] = rsqrtf((float)cnt[i] + 1.0f);   // deg includes self-loop, always >= 1
}

__global__ void k_fill(const int* __restrict__ src, const int* __restrict__ dst,
                       int* __restrict__ cursor, int* __restrict__ csr, int E) {
  int e = blockIdx.x * blockDim.x + threadIdx.x;
  if (e >= E) return;
  int p = atomicAdd(&cursor[dst[e]], 1);
  csr[p] = src[e];
}

// ---------------- GEMM: Y[N x M] = dinv[r] * (X[N x K] @ W[K x M]) ----------------
// 4 rows x 4 cols per thread; W row chunks as float4 (wave-broadcast, cache-hot)

template <int K, int M>
__global__ __launch_bounds__(256) void k_gemm(const float* __restrict__ X,
                                              const float* __restrict__ W,
                                              const float* __restrict__ dinv,
                                              float* __restrict__ Y, int N) {
  constexpr int JC = M / 4;
  int gid = blockIdx.x * blockDim.x + threadIdx.x;
  int rg = gid / JC;
  int jc = (gid - rg * JC) * 4;
  int r0 = rg * 4;
  if (r0 >= N) return;
  int r1 = min(r0 + 1, N - 1), r2 = min(r0 + 2, N - 1), r3 = min(r0 + 3, N - 1);
  const float* x0 = X + (size_t)r0 * K;
  const float* x1 = X + (size_t)r1 * K;
  const float* x2 = X + (size_t)r2 * K;
  const float* x3 = X + (size_t)r3 * K;
  float4 a0 = {0,0,0,0}, a1 = {0,0,0,0}, a2 = {0,0,0,0}, a3 = {0,0,0,0};
#pragma unroll 4
  for (int k = 0; k < K; ++k) {
    float4 w = *(const float4*)(W + k * M + jc);
    float v0 = x0[k], v1 = x1[k], v2 = x2[k], v3 = x3[k];
    a0.x = fmaf(v0, w.x, a0.x); a0.y = fmaf(v0, w.y, a0.y);
    a0.z = fmaf(v0, w.z, a0.z); a0.w = fmaf(v0, w.w, a0.w);
    a1.x = fmaf(v1, w.x, a1.x); a1.y = fmaf(v1, w.y, a1.y);
    a1.z = fmaf(v1, w.z, a1.z); a1.w = fmaf(v1, w.w, a1.w);
    a2.x = fmaf(v2, w.x, a2.x); a2.y = fmaf(v2, w.y, a2.y);
    a2.z = fmaf(v2, w.z, a2.z); a2.w = fmaf(v2, w.w, a2.w);
    a3.x = fmaf(v3, w.x, a3.x); a3.y = fmaf(v3, w.y, a3.y);
    a3.z = fmaf(v3, w.z, a3.z); a3.w = fmaf(v3, w.w, a3.w);
  }
  float d0 = dinv[r0];
  *(float4*)(Y + (size_t)r0 * M + jc) = make_float4(a0.x*d0, a0.y*d0, a0.z*d0, a0.w*d0);
  if (r0 + 1 < N) { float d = dinv[r1];
    *(float4*)(Y + (size_t)r1 * M + jc) = make_float4(a1.x*d, a1.y*d, a1.z*d, a1.w*d); }
  if (r0 + 2 < N) { float d = dinv[r2];
    *(float4*)(Y + (size_t)r2 * M + jc) = make_float4(a2.x*d, a2.y*d, a2.z*d, a2.w*d); }
  if (r0 + 3 < N) { float d = dinv[r3];
    *(float4*)(Y + (size_t)r3 * M + jc) = make_float4(a3.x*d, a3.y*d, a3.z*d, a3.w*d); }
}

// ---------------- Aggregation ----------------
// Hs is pre-scaled by dinv (in GEMM epilogue).
// out[n,f4] = dinv[n] * (Hs[n,f4] + sum_s Hs[s,f4]) + b[f4]; optional relu.
// One thread per (node, 4 features); edge loop unrolled x4 for MLP.

template <int M, bool RELU>
__global__ __launch_bounds__(256) void k_agg(const float* __restrict__ Hs,
                                             const int* __restrict__ csr,
                                             const int* __restrict__ rs,
                                             const int* __restrict__ cnt,
                                             const float* __restrict__ dinv,
                                             const float* __restrict__ bias,
                                             float* __restrict__ out, int N) {
  constexpr int JC = M / 4;
  int gid = blockIdx.x * blockDim.x + threadIdx.x;
  int n = gid / JC;
  if (n >= N) return;
  int f4 = (gid - n * JC) * 4;
  float dn = dinv[n];
  float4 acc = *(const float4*)(Hs + (size_t)n * M + f4);   // self-loop term
  int p = rs[n];
  int e = cnt[n];
  int i = 0;
  for (; i + 4 <= e; i += 4) {
    int s0 = csr[p + i];
    int s1 = csr[p + i + 1];
    int s2 = csr[p + i + 2];
    int s3 = csr[p + i + 3];
    float4 h0 = *(const float4*)(Hs + (size_t)s0 * M + f4);
    float4 h1 = *(const float4*)(Hs + (size_t)s1 * M + f4);
    float4 h2 = *(const float4*)(Hs + (size_t)s2 * M + f4);
    float4 h3 = *(const float4*)(Hs + (size_t)s3 * M + f4);
    acc.x += (h0.x + h1.x) + (h2.x + h3.x);
    acc.y += (h0.y + h1.y) + (h2.y + h3.y);
    acc.z += (h0.z + h1.z) + (h2.z + h3.z);
    acc.w += (h0.w + h1.w) + (h2.w + h3.w);
  }
  for (; i < e; ++i) {
    int s = csr[p + i];
    float4 h = *(const float4*)(Hs + (size_t)s * M + f4);
    acc.x += h.x; acc.y += h.y; acc.z += h.z; acc.w += h.w;
  }
  float4 b = *(const float4*)(bias + f4);
  float4 r;
  r.x = fmaf(dn, acc.x, b.x);
  r.y = fmaf(dn, acc.y, b.y);
  r.z = fmaf(dn, acc.z, b.z);
  r.w = fmaf(dn, acc.w, b.w);
  if (RELU) {
    r.x = fmaxf(r.x, 0.0f); r.y = fmaxf(r.y, 0.0f);
    r.z = fmaxf(r.z, 0.0f); r.w = fmaxf(r.w, 0.0f);
  }
  *(float4*)(out + (size_t)n * M + f4) = r;
}

// ---------------- launch ----------------

extern "C" void kernel_launch(void* const* d_in, const int* in_sizes, int n_in,
                              void* d_out, int out_size, void* d_ws, size_t ws_size,
                              hipStream_t stream) {
  const float* x  = (const float*)d_in[0];
  const int*   ei = (const int*)d_in[1];
  const float* W1 = (const float*)d_in[2];
  const float* b1 = (const float*)d_in[3];
  const float* W2 = (const float*)d_in[4];
  const float* b2 = (const float*)d_in[5];
  float* out = (float*)d_out;

  const int N = in_sizes[0] / IN_C;     // 50000
  const int E = in_sizes[1] / 2;        // 800000
  const int* src = ei;
  const int* dst = ei + E;

  char* ws = (char*)d_ws;
  size_t off = 0;
  auto alloc = [&](size_t bytes) -> void* {
    void* p = ws + off;
    off = (off + bytes + 255) & ~(size_t)255;
    return p;
  };
  int*   cnt    = (int*)alloc((size_t)N * 4);
  int*   rs     = (int*)alloc((size_t)N * 4);
  int*   cursor = (int*)alloc((size_t)N * 4);
  float* dinv   = (float*)alloc((size_t)N * 4);
  int*   bsum   = (int*)alloc(256 * 4);
  int*   boff   = (int*)alloc(256 * 4);
  int*   junk   = (int*)alloc(256 * 4);
  int*   csr    = (int*)alloc((size_t)E * 4);
  float* h1     = (float*)alloc((size_t)N * HID * 4);   // reused as h2 later
  float* h      = (float*)alloc((size_t)N * HID * 4);

  const int nbN = (N + 255) / 256;
  const int nbE = (E + 255) / 256;

  hipMemsetAsync(cnt, 0, (size_t)N * 4, stream);
  k_count<<<nbE, 256, 0, stream>>>(dst, cnt, E);
  k_scan_block<<<nbN, 256, 0, stream>>>(cnt, rs, bsum, N);
  k_scan_block<<<1, 256, 0, stream>>>(bsum, boff, junk, nbN);
  k_finish<<<nbN, 256, 0, stream>>>(rs, boff, cursor, cnt, dinv, N);
  k_fill<<<nbE, 256, 0, stream>>>(src, dst, cursor, csr, E);

  // layer 1: h1 = dinv * (x @ W1) ; h = relu(dinv*(agg(h1)) + b1)
  {
    int threads = ((N + 3) / 4) * (HID / 4);
    k_gemm<IN_C, HID><<<(threads + 255) / 256, 256, 0, stream>>>(x, W1, dinv, h1, N);
    int t2 = N * (HID / 4);
    k_agg<HID, true><<<(t2 + 255) / 256, 256, 0, stream>>>(h1, csr, rs, cnt, dinv, b1, h, N);
  }
  // layer 2: h2 = dinv * (h @ W2) (into h1 buffer) ; out = dinv*agg(h2) + b2
  {
    int threads = ((N + 3) / 4) * (OUT_C / 4);
    k_gemm<HID, OUT_C><<<(threads + 255) / 256, 256, 0, stream>>>(h, W2, dinv, h1, N);
    int t2 = N * (OUT_C / 4);
    k_agg<OUT_C, false><<<(t2 + 255) / 256, 256, 0, stream>>>(h1, csr, rs, cnt, dinv, b2, out, N);
  }
}

// Round 3
// 199.051 us; speedup vs baseline: 1.7826x; 1.1862x over previous
//
#include <hip/hip_runtime.h>

static constexpr int IN_C  = 128;
static constexpr int HID   = 96;
static constexpr int OUT_C = 48;

static constexpr int NPART     = 8;     // XCD count on MI355X (perf heuristic only)
static constexpr int FILL_ITER = 16;
static constexpr int CHUNK     = 256 * FILL_ITER;  // edges per chunk

// ---------------- CSR build ----------------

// count in-degree AND record each edge's slot within its dst segment
__global__ void k_count(const int* __restrict__ dst, int* __restrict__ cnt,
                        int* __restrict__ perm, int E) {
  int e = blockIdx.x * blockDim.x + threadIdx.x;
  if (e < E) perm[e] = atomicAdd(&cnt[dst[e]], 1);
}

// exclusive block scan (256/block), emits per-block total
__global__ void k_scan_block(const int* __restrict__ in, int* __restrict__ out_excl,
                             int* __restrict__ bsum, int n) {
  __shared__ int sm[256];
  int i = blockIdx.x * 256 + threadIdx.x;
  int v = (i < n) ? in[i] : 0;
  int val = v;
  sm[threadIdx.x] = val;
  __syncthreads();
  for (int off = 1; off < 256; off <<= 1) {
    int t = (threadIdx.x >= (unsigned)off) ? sm[threadIdx.x - off] : 0;
    __syncthreads();
    val += t;
    sm[threadIdx.x] = val;
    __syncthreads();
  }
  if (i < n) out_excl[i] = val - v;
  if (threadIdx.x == 255) bsum[blockIdx.x] = val;
}

__global__ void k_finish(int* __restrict__ rs, const int* __restrict__ boff,
                         const int* __restrict__ cnt,
                         float* __restrict__ dinv, int n) {
  int i = blockIdx.x * 256 + threadIdx.x;
  if (i >= n) return;
  rs[i] = rs[i] + boff[blockIdx.x];
  dinv[i] = rsqrtf((float)cnt[i] + 1.0f);   // deg includes self-loop, always >= 1
}

// Partitioned fill: workgroup (x, y) scans edge-chunk y, writes only edges with
// dst in partition x -> each partition's csr writes land in a contiguous slice,
// merging fully in one XCD's L2 (bid = x + 8*y, round-robin XCD placement).
__global__ __launch_bounds__(256) void k_fill_part(
    const int* __restrict__ src, const int* __restrict__ dst,
    const int* __restrict__ perm, const int* __restrict__ rs,
    int* __restrict__ csr, int E, int P) {
  int lo = blockIdx.x * P;
  int hi = lo + P;
  int base = blockIdx.y * CHUNK + threadIdx.x;
#pragma unroll
  for (int i = 0; i < FILL_ITER; ++i) {
    int e = base + i * 256;
    if (e < E) {
      int d = dst[e];
      if (d >= lo && d < hi) {
        csr[rs[d] + perm[e]] = src[e];
      }
    }
  }
}

// ---------------- GEMM: Y[N x M] = dinv[r] * (X[N x K] @ W[K x M]) ----------------

template <int K, int M>
__global__ __launch_bounds__(256) void k_gemm(const float* __restrict__ X,
                                              const float* __restrict__ W,
                                              const float* __restrict__ dinv,
                                              float* __restrict__ Y, int N) {
  constexpr int JC = M / 4;
  int gid = blockIdx.x * blockDim.x + threadIdx.x;
  int rg = gid / JC;
  int jc = (gid - rg * JC) * 4;
  int r0 = rg * 4;
  if (r0 >= N) return;
  int r1 = min(r0 + 1, N - 1), r2 = min(r0 + 2, N - 1), r3 = min(r0 + 3, N - 1);
  const float* x0 = X + (size_t)r0 * K;
  const float* x1 = X + (size_t)r1 * K;
  const float* x2 = X + (size_t)r2 * K;
  const float* x3 = X + (size_t)r3 * K;
  float4 a0 = {0,0,0,0}, a1 = {0,0,0,0}, a2 = {0,0,0,0}, a3 = {0,0,0,0};
#pragma unroll 4
  for (int k = 0; k < K; ++k) {
    float4 w = *(const float4*)(W + k * M + jc);
    float v0 = x0[k], v1 = x1[k], v2 = x2[k], v3 = x3[k];
    a0.x = fmaf(v0, w.x, a0.x); a0.y = fmaf(v0, w.y, a0.y);
    a0.z = fmaf(v0, w.z, a0.z); a0.w = fmaf(v0, w.w, a0.w);
    a1.x = fmaf(v1, w.x, a1.x); a1.y = fmaf(v1, w.y, a1.y);
    a1.z = fmaf(v1, w.z, a1.z); a1.w = fmaf(v1, w.w, a1.w);
    a2.x = fmaf(v2, w.x, a2.x); a2.y = fmaf(v2, w.y, a2.y);
    a2.z = fmaf(v2, w.z, a2.z); a2.w = fmaf(v2, w.w, a2.w);
    a3.x = fmaf(v3, w.x, a3.x); a3.y = fmaf(v3, w.y, a3.y);
    a3.z = fmaf(v3, w.z, a3.z); a3.w = fmaf(v3, w.w, a3.w);
  }
  float d0 = dinv[r0];
  *(float4*)(Y + (size_t)r0 * M + jc) = make_float4(a0.x*d0, a0.y*d0, a0.z*d0, a0.w*d0);
  if (r0 + 1 < N) { float d = dinv[r1];
    *(float4*)(Y + (size_t)r1 * M + jc) = make_float4(a1.x*d, a1.y*d, a1.z*d, a1.w*d); }
  if (r0 + 2 < N) { float d = dinv[r2];
    *(float4*)(Y + (size_t)r2 * M + jc) = make_float4(a2.x*d, a2.y*d, a2.z*d, a2.w*d); }
  if (r0 + 3 < N) { float d = dinv[r3];
    *(float4*)(Y + (size_t)r3 * M + jc) = make_float4(a3.x*d, a3.y*d, a3.z*d, a3.w*d); }
}

// ---------------- Aggregation ----------------
// Hs is pre-scaled by dinv (in GEMM epilogue).
// out[n,f4] = dinv[n] * (Hs[n,f4] + sum_s Hs[s,f4]) + b[f4]; optional relu.

template <int M, bool RELU>
__global__ __launch_bounds__(256) void k_agg(const float* __restrict__ Hs,
                                             const int* __restrict__ csr,
                                             const int* __restrict__ rs,
                                             const int* __restrict__ cnt,
                                             const float* __restrict__ dinv,
                                             const float* __restrict__ bias,
                                             float* __restrict__ out, int N) {
  constexpr int JC = M / 4;
  int gid = blockIdx.x * blockDim.x + threadIdx.x;
  int n = gid / JC;
  if (n >= N) return;
  int f4 = (gid - n * JC) * 4;
  float dn = dinv[n];
  float4 acc = *(const float4*)(Hs + (size_t)n * M + f4);   // self-loop term
  int p = rs[n];
  int e = cnt[n];
  int i = 0;
  for (; i + 4 <= e; i += 4) {
    int s0 = csr[p + i];
    int s1 = csr[p + i + 1];
    int s2 = csr[p + i + 2];
    int s3 = csr[p + i + 3];
    float4 h0 = *(const float4*)(Hs + (size_t)s0 * M + f4);
    float4 h1 = *(const float4*)(Hs + (size_t)s1 * M + f4);
    float4 h2 = *(const float4*)(Hs + (size_t)s2 * M + f4);
    float4 h3 = *(const float4*)(Hs + (size_t)s3 * M + f4);
    acc.x += (h0.x + h1.x) + (h2.x + h3.x);
    acc.y += (h0.y + h1.y) + (h2.y + h3.y);
    acc.z += (h0.z + h1.z) + (h2.z + h3.z);
    acc.w += (h0.w + h1.w) + (h2.w + h3.w);
  }
  for (; i < e; ++i) {
    int s = csr[p + i];
    float4 h = *(const float4*)(Hs + (size_t)s * M + f4);
    acc.x += h.x; acc.y += h.y; acc.z += h.z; acc.w += h.w;
  }
  float4 b = *(const float4*)(bias + f4);
  float4 r;
  r.x = fmaf(dn, acc.x, b.x);
  r.y = fmaf(dn, acc.y, b.y);
  r.z = fmaf(dn, acc.z, b.z);
  r.w = fmaf(dn, acc.w, b.w);
  if (RELU) {
    r.x = fmaxf(r.x, 0.0f); r.y = fmaxf(r.y, 0.0f);
    r.z = fmaxf(r.z, 0.0f); r.w = fmaxf(r.w, 0.0f);
  }
  *(float4*)(out + (size_t)n * M + f4) = r;
}

// ---------------- launch ----------------

extern "C" void kernel_launch(void* const* d_in, const int* in_sizes, int n_in,
                              void* d_out, int out_size, void* d_ws, size_t ws_size,
                              hipStream_t stream) {
  const float* x  = (const float*)d_in[0];
  const int*   ei = (const int*)d_in[1];
  const float* W1 = (const float*)d_in[2];
  const float* b1 = (const float*)d_in[3];
  const float* W2 = (const float*)d_in[4];
  const float* b2 = (const float*)d_in[5];
  float* out = (float*)d_out;

  const int N = in_sizes[0] / IN_C;     // 50000
  const int E = in_sizes[1] / 2;        // 800000
  const int* src = ei;
  const int* dst = ei + E;

  char* ws = (char*)d_ws;
  size_t off = 0;
  auto alloc = [&](size_t bytes) -> void* {
    void* p = ws + off;
    off = (off + bytes + 255) & ~(size_t)255;
    return p;
  };
  int*   cnt    = (int*)alloc((size_t)N * 4);
  int*   rs     = (int*)alloc((size_t)N * 4);
  float* dinv   = (float*)alloc((size_t)N * 4);
  int*   bsum   = (int*)alloc(256 * 4);
  int*   boff   = (int*)alloc(256 * 4);
  int*   junk   = (int*)alloc(256 * 4);
  int*   perm   = (int*)alloc((size_t)E * 4);
  int*   csr    = (int*)alloc((size_t)E * 4);
  float* h1     = (float*)alloc((size_t)N * HID * 4);   // reused as h2 later
  float* h      = (float*)alloc((size_t)N * HID * 4);

  const int nbN = (N + 255) / 256;
  const int nbE = (E + 255) / 256;
  const int P   = (N + NPART - 1) / NPART;

  hipMemsetAsync(cnt, 0, (size_t)N * 4, stream);
  k_count<<<nbE, 256, 0, stream>>>(dst, cnt, perm, E);
  k_scan_block<<<nbN, 256, 0, stream>>>(cnt, rs, bsum, N);
  k_scan_block<<<1, 256, 0, stream>>>(bsum, boff, junk, nbN);
  k_finish<<<nbN, 256, 0, stream>>>(rs, boff, cnt, dinv, N);
  dim3 fg(NPART, (E + CHUNK - 1) / CHUNK);
  k_fill_part<<<fg, 256, 0, stream>>>(src, dst, perm, rs, csr, E, P);

  // layer 1: h1 = dinv * (x @ W1) ; h = relu(dinv*(agg(h1)) + b1)
  {
    int threads = ((N + 3) / 4) * (HID / 4);
    k_gemm<IN_C, HID><<<(threads + 255) / 256, 256, 0, stream>>>(x, W1, dinv, h1, N);
    int t2 = N * (HID / 4);
    k_agg<HID, true><<<(t2 + 255) / 256, 256, 0, stream>>>(h1, csr, rs, cnt, dinv, b1, h, N);
  }
  // layer 2: h2 = dinv * (h @ W2) (into h1 buffer) ; out = dinv*agg(h2) + b2
  {
    int threads = ((N + 3) / 4) * (OUT_C / 4);
    k_gemm<HID, OUT_C><<<(threads + 255) / 256, 256, 0, stream>>>(h, W2, dinv, h1, N);
    int t2 = N * (OUT_C / 4);
    k_agg<OUT_C, false><<<(t2 + 255) / 256, 256, 0, stream>>>(h1, csr, rs, cnt, dinv, b2, out, N);
  }
}

// Round 6
// 198.338 us; speedup vs baseline: 1.7890x; 1.0036x over previous
//
#include <hip/hip_runtime.h>

static constexpr int IN_C  = 128;
static constexpr int HID   = 96;
static constexpr int OUT_C = 48;

static constexpr int NPART     = 8;     // XCD count on MI355X (perf heuristic only)
static constexpr int FILL_ITER = 16;
static constexpr int CHUNK     = 256 * FILL_ITER;  // edges per chunk

// ---------------- CSR build ----------------

// count in-degree AND record each edge's slot within its dst segment
__global__ void k_count(const int* __restrict__ dst, int* __restrict__ cnt,
                        int* __restrict__ perm, int E) {
  int e = blockIdx.x * blockDim.x + threadIdx.x;
  if (e < E) perm[e] = atomicAdd(&cnt[dst[e]], 1);
}

// exclusive block scan (256/block), emits per-block total
__global__ void k_scan_block(const int* __restrict__ in, int* __restrict__ out_excl,
                             int* __restrict__ bsum, int n) {
  __shared__ int sm[256];
  int i = blockIdx.x * 256 + threadIdx.x;
  int v = (i < n) ? in[i] : 0;
  int val = v;
  sm[threadIdx.x] = val;
  __syncthreads();
  for (int off = 1; off < 256; off <<= 1) {
    int t = (threadIdx.x >= (unsigned)off) ? sm[threadIdx.x - off] : 0;
    __syncthreads();
    val += t;
    sm[threadIdx.x] = val;
    __syncthreads();
  }
  if (i < n) out_excl[i] = val - v;
  if (threadIdx.x == 255) bsum[blockIdx.x] = val;
}

__global__ void k_finish(int* __restrict__ rs, const int* __restrict__ boff,
                         const int* __restrict__ cnt,
                         float* __restrict__ dinv, int n) {
  int i = blockIdx.x * 256 + threadIdx.x;
  if (i >= n) return;
  rs[i] = rs[i] + boff[blockIdx.x];
  dinv[i] = rsqrtf((float)cnt[i] + 1.0f);   // deg includes self-loop, always >= 1
}

// Partitioned fill: workgroup (x, y) scans edge-chunk y, writes only edges with
// dst in partition x -> each partition's csr writes land in a contiguous slice,
// merging fully in one XCD's L2 (bid = x + 8*y, round-robin XCD placement).
__global__ __launch_bounds__(256) void k_fill_part(
    const int* __restrict__ src, const int* __restrict__ dst,
    const int* __restrict__ perm, const int* __restrict__ rs,
    int* __restrict__ csr, int E, int P) {
  int lo = blockIdx.x * P;
  int hi = lo + P;
  int base = blockIdx.y * CHUNK + threadIdx.x;
#pragma unroll
  for (int i = 0; i < FILL_ITER; ++i) {
    int e = base + i * 256;
    if (e < E) {
      int d = dst[e];
      if (d >= lo && d < hi) {
        csr[rs[d] + perm[e]] = src[e];
      }
    }
  }
}

// ---------------- GEMM: Y[N x M] = dinv[r] * (X[N x K] @ W[K x M]) ----------------
// 8 rows x 4 cols per thread; k-loop steps by 4 with float4 X and W loads:
// 12 VMEM per 128 FMA (vs 20 per 64 before).

__device__ __forceinline__ void fma4(float4& a, float s, const float4& w) {
  a.x = fmaf(s, w.x, a.x); a.y = fmaf(s, w.y, a.y);
  a.z = fmaf(s, w.z, a.z); a.w = fmaf(s, w.w, a.w);
}

template <int K, int M>
__global__ __launch_bounds__(256) void k_gemm(const float* __restrict__ X,
                                              const float* __restrict__ W,
                                              const float* __restrict__ dinv,
                                              float* __restrict__ Y, int N) {
  constexpr int JC = M / 4;
  int gid = blockIdx.x * blockDim.x + threadIdx.x;
  int rg = gid / JC;
  int jc = (gid - rg * JC) * 4;
  int r0 = rg * 8;
  if (r0 >= N) return;
  float4 acc[8] = {};

  if (r0 + 8 <= N) {                       // fast path (always, when N % 8 == 0)
    const float* xb = X + (size_t)r0 * K;
    for (int k = 0; k < K; k += 4) {
      const float* wk = W + (size_t)k * M + jc;
      float4 w0 = *(const float4*)(wk);
      float4 w1 = *(const float4*)(wk + M);
      float4 w2 = *(const float4*)(wk + 2 * M);
      float4 w3 = *(const float4*)(wk + 3 * M);
#pragma unroll
      for (int i = 0; i < 8; ++i) {
        float4 xv = *(const float4*)(xb + i * K + k);
        fma4(acc[i], xv.x, w0);
        fma4(acc[i], xv.y, w1);
        fma4(acc[i], xv.z, w2);
        fma4(acc[i], xv.w, w3);
      }
    }
#pragma unroll
    for (int i = 0; i < 8; ++i) {
      float d = dinv[r0 + i];
      *(float4*)(Y + (size_t)(r0 + i) * M + jc) =
          make_float4(acc[i].x * d, acc[i].y * d, acc[i].z * d, acc[i].w * d);
    }
  } else {                                  // tail path (clamped rows)
    for (int k = 0; k < K; k += 4) {
      const float* wk = W + (size_t)k * M + jc;
      float4 w0 = *(const float4*)(wk);
      float4 w1 = *(const float4*)(wk + M);
      float4 w2 = *(const float4*)(wk + 2 * M);
      float4 w3 = *(const float4*)(wk + 3 * M);
#pragma unroll
      for (int i = 0; i < 8; ++i) {
        int r = min(r0 + i, N - 1);
        float4 xv = *(const float4*)(X + (size_t)r * K + k);
        fma4(acc[i], xv.x, w0);
        fma4(acc[i], xv.y, w1);
        fma4(acc[i], xv.z, w2);
        fma4(acc[i], xv.w, w3);
      }
    }
#pragma unroll
    for (int i = 0; i < 8; ++i) {
      if (r0 + i < N) {
        float d = dinv[r0 + i];
        *(float4*)(Y + (size_t)(r0 + i) * M + jc) =
            make_float4(acc[i].x * d, acc[i].y * d, acc[i].z * d, acc[i].w * d);
      }
    }
  }
}

// ---------------- Aggregation ----------------
// Hs is pre-scaled by dinv (in GEMM epilogue).
// out[n,f4] = dinv[n] * (Hs[n,f4] + sum_s Hs[s,f4]) + b[f4]; optional relu.

template <int M, bool RELU>
__global__ __launch_bounds__(256) void k_agg(const float* __restrict__ Hs,
                                             const int* __restrict__ csr,
                                             const int* __restrict__ rs,
                                             const int* __restrict__ cnt,
                                             const float* __restrict__ dinv,
                                             const float* __restrict__ bias,
                                             float* __restrict__ out, int N) {
  constexpr int JC = M / 4;
  int gid = blockIdx.x * blockDim.x + threadIdx.x;
  int n = gid / JC;
  if (n >= N) return;
  int f4 = (gid - n * JC) * 4;
  float dn = dinv[n];
  float4 acc = *(const float4*)(Hs + (size_t)n * M + f4);   // self-loop term
  int p = rs[n];
  int e = cnt[n];
  int i = 0;
  for (; i + 4 <= e; i += 4) {
    int s0 = csr[p + i];
    int s1 = csr[p + i + 1];
    int s2 = csr[p + i + 2];
    int s3 = csr[p + i + 3];
    float4 h0 = *(const float4*)(Hs + (size_t)s0 * M + f4);
    float4 h1 = *(const float4*)(Hs + (size_t)s1 * M + f4);
    float4 h2 = *(const float4*)(Hs + (size_t)s2 * M + f4);
    float4 h3 = *(const float4*)(Hs + (size_t)s3 * M + f4);
    acc.x += (h0.x + h1.x) + (h2.x + h3.x);
    acc.y += (h0.y + h1.y) + (h2.y + h3.y);
    acc.z += (h0.z + h1.z) + (h2.z + h3.z);
    acc.w += (h0.w + h1.w) + (h2.w + h3.w);
  }
  for (; i < e; ++i) {
    int s = csr[p + i];
    float4 h = *(const float4*)(Hs + (size_t)s * M + f4);
    acc.x += h.x; acc.y += h.y; acc.z += h.z; acc.w += h.w;
  }
  float4 b = *(const float4*)(bias + f4);
  float4 r;
  r.x = fmaf(dn, acc.x, b.x);
  r.y = fmaf(dn, acc.y, b.y);
  r.z = fmaf(dn, acc.z, b.z);
  r.w = fmaf(dn, acc.w, b.w);
  if (RELU) {
    r.x = fmaxf(r.x, 0.0f); r.y = fmaxf(r.y, 0.0f);
    r.z = fmaxf(r.z, 0.0f); r.w = fmaxf(r.w, 0.0f);
  }
  *(float4*)(out + (size_t)n * M + f4) = r;
}

// ---------------- launch ----------------

extern "C" void kernel_launch(void* const* d_in, const int* in_sizes, int n_in,
                              void* d_out, int out_size, void* d_ws, size_t ws_size,
                              hipStream_t stream) {
  const float* x  = (const float*)d_in[0];
  const int*   ei = (const int*)d_in[1];
  const float* W1 = (const float*)d_in[2];
  const float* b1 = (const float*)d_in[3];
  const float* W2 = (const float*)d_in[4];
  const float* b2 = (const float*)d_in[5];
  float* out = (float*)d_out;

  const int N = in_sizes[0] / IN_C;     // 50000
  const int E = in_sizes[1] / 2;        // 800000
  const int* src = ei;
  const int* dst = ei + E;

  char* ws = (char*)d_ws;
  size_t off = 0;
  auto alloc = [&](size_t bytes) -> void* {
    void* p = ws + off;
    off = (off + bytes + 255) & ~(size_t)255;
    return p;
  };
  int*   cnt    = (int*)alloc((size_t)N * 4);
  int*   rs     = (int*)alloc((size_t)N * 4);
  float* dinv   = (float*)alloc((size_t)N * 4);
  int*   bsum   = (int*)alloc(256 * 4);
  int*   boff   = (int*)alloc(256 * 4);
  int*   junk   = (int*)alloc(256 * 4);
  int*   perm   = (int*)alloc((size_t)E * 4);
  int*   csr    = (int*)alloc((size_t)E * 4);
  float* h1     = (float*)alloc((size_t)N * HID * 4);   // reused as h2 later
  float* h      = (float*)alloc((size_t)N * HID * 4);

  const int nbN = (N + 255) / 256;
  const int nbE = (E + 255) / 256;
  const int P   = (N + NPART - 1) / NPART;

  hipMemsetAsync(cnt, 0, (size_t)N * 4, stream);
  k_count<<<nbE, 256, 0, stream>>>(dst, cnt, perm, E);
  k_scan_block<<<nbN, 256, 0, stream>>>(cnt, rs, bsum, N);
  k_scan_block<<<1, 256, 0, stream>>>(bsum, boff, junk, nbN);
  k_finish<<<nbN, 256, 0, stream>>>(rs, boff, cnt, dinv, N);
  dim3 fg(NPART, (E + CHUNK - 1) / CHUNK);
  k_fill_part<<<fg, 256, 0, stream>>>(src, dst, perm, rs, csr, E, P);

  // layer 1: h1 = dinv * (x @ W1) ; h = relu(dinv*(agg(h1)) + b1)
  {
    int threads = ((N + 7) / 8) * (HID / 4);
    k_gemm<IN_C, HID><<<(threads + 255) / 256, 256, 0, stream>>>(x, W1, dinv, h1, N);
    int t2 = N * (HID / 4);
    k_agg<HID, true><<<(t2 + 255) / 256, 256, 0, stream>>>(h1, csr, rs, cnt, dinv, b1, h, N);
  }
  // layer 2: h2 = dinv * (h @ W2) (into h1 buffer) ; out = dinv*agg(h2) + b2
  {
    int threads = ((N + 7) / 8) * (OUT_C / 4);
    k_gemm<HID, OUT_C><<<(threads + 255) / 256, 256, 0, stream>>>(h, W2, dinv, h1, N);
    int t2 = N * (OUT_C / 4);
    k_agg<OUT_C, false><<<(t2 + 255) / 256, 256, 0, stream>>>(h1, csr, rs, cnt, dinv, b2, out, N);
  }
}